// Round 3
// baseline (197.631 us; speedup 1.0000x reference)
//
#include <hip/hip_runtime.h>

// YOLO loss: pred/target (N,14,14,30) fp32 -> scalar.
// S=14, B=2, C=20, cell stride = 30 floats = 120 bytes.
//
// R2: (a) two-phase LDS staging — one 31 KB buffer reused for pred then tgt,
// doubling occupancy vs R1's 62 KB; (b) fused final reduction via
// last-block-arrival (agent-scope atomics, counter zeroed by hipMemsetAsync).

#define S_DIM 14
#define CELLF 30
#define TPB 256
#define CHUNKF (TPB * CELLF)   // 7680 floats per array per block
#define CHUNK4 (CHUNKF / 4)    // 1920 float4 per array per block

constexpr float LAMBDA_COORD = 5.0f;
constexpr float LAMBDA_NOOBJ = 0.5f;
constexpr float EPSF = 1e-7f;

__device__ __forceinline__ float iou_xywh(float cx1, float cy1, float w1, float h1,
                                          float cx2, float cy2, float w2, float h2) {
    float ix1 = fmaxf(cx1 - 0.5f * w1, cx2 - 0.5f * w2);
    float iy1 = fmaxf(cy1 - 0.5f * h1, cy2 - 0.5f * h2);
    float ix2 = fminf(cx1 + 0.5f * w1, cx2 + 0.5f * w2);
    float iy2 = fminf(cy1 + 0.5f * h1, cy2 + 0.5f * h2);
    float inter = fmaxf(ix2 - ix1, 0.0f) * fmaxf(iy2 - iy1, 0.0f);
    float uni = w1 * h1 + w2 * h2 - inter + EPSF;
    return inter / uni;
}

// Stage one array's block-chunk (CHUNK4 float4) into lds, then read this
// thread's cell into dst[30]. Caller must NOT rely on lds afterwards.
__device__ __forceinline__ void stage_and_gather(
        const float4* __restrict__ src4, size_t base4, size_t n4,
        float* lds, int tid, float dst[CELLF]) {
    float4 st[8];
    #pragma unroll
    for (int k = 0; k < 8; ++k) {
        int i = tid + k * TPB;
        if (i < CHUNK4) {
            size_t gi = base4 + i;
            if (gi >= n4) gi = n4 - 1;   // clamp (no-op for exact grids)
            st[k] = src4[gi];
        }
    }
    #pragma unroll
    for (int k = 0; k < 8; ++k) {
        int i = tid + k * TPB;
        if (i < CHUNK4)
            reinterpret_cast<float4*>(lds)[i] = st[k];
    }
    __syncthreads();
    #pragma unroll
    for (int k = 0; k < CELLF; ++k) dst[k] = lds[tid * CELLF + k];  // stride-30: 2-way, free
    __syncthreads();
}

__global__ __launch_bounds__(TPB) void yolo_loss_kernel(
        const float* __restrict__ pred,
        const float* __restrict__ tgt,
        float* __restrict__ partial,
        unsigned* __restrict__ counter,
        float* __restrict__ out,
        int ncells, int nblocks, float inv_n) {
    __shared__ float lds[CHUNKF];   // 30720 B -> ~4-5 blocks/CU

    const int tid = threadIdx.x;
    const size_t base4 = (size_t)blockIdx.x * CHUNK4;
    const size_t n4 = (size_t)ncells * CELLF / 4;

    float p[CELLF], t[CELLF];
    stage_and_gather(reinterpret_cast<const float4*>(pred), base4, n4, lds, tid, p);
    stage_and_gather(reinterpret_cast<const float4*>(tgt),  base4, n4, lds, tid, t);

    int cell = blockIdx.x * TPB + tid;
    float loss = 0.0f;
    if (cell < ncells) {
        // layout per cell: [0..4]=box0 cx,cy,w,h,conf  [5..9]=box1  [10..29]=classes
        float iou00 = iou_xywh(p[0], p[1], p[2], p[3], t[0], t[1], t[2], t[3]);
        float iou10 = iou_xywh(p[5], p[6], p[7], p[8], t[0], t[1], t[2], t[3]);
        float iou11 = iou_xywh(p[5], p[6], p[7], p[8], t[5], t[6], t[7], t[8]);

        bool obj = t[4] > 0.0f;          // tgt conf of box0 (== obj mask)
        bool best1 = iou10 > iou00;      // argmax first-max tie-break

        float d0 = p[4] - t[4];  float c0 = d0 * d0;
        float d1 = p[9] - t[9];  float c1 = d1 * d1;
        float conf_best  = best1 ? c1 : c0;
        float conf_other = best1 ? c0 : c1;

        float iou_pair_best = best1 ? iou11 : iou00;
        float coord = 1.0f - sqrtf(fmaxf(iou_pair_best, EPSF));  // ALPHA=0.5

        float cls = 0.0f;
        #pragma unroll
        for (int k = 0; k < 20; ++k) {
            float d = p[10 + k] - t[10 + k];
            cls = fmaf(d, d, cls);
        }

        float loss_obj   = obj ? conf_best : 0.0f;
        float loss_noobj = obj ? conf_other : (c0 + c1);
        float loss_coord = obj ? coord : 0.0f;
        float loss_cls   = obj ? cls : 0.0f;

        loss = LAMBDA_COORD * loss_coord + loss_obj + LAMBDA_NOOBJ * loss_noobj + loss_cls;
    }

    // ---- block reduce (wave shuffle + LDS)
    #pragma unroll
    for (int off = 32; off > 0; off >>= 1)
        loss += __shfl_down(loss, off, 64);

    __shared__ float wsum[4];
    __shared__ int amLast;
    int lane = tid & 63;
    int wid  = tid >> 6;
    if (lane == 0) wsum[wid] = loss;
    __syncthreads();

    if (tid == 0) {
        float bsum = wsum[0] + wsum[1] + wsum[2] + wsum[3];
        __hip_atomic_store(&partial[blockIdx.x], bsum,
                           __ATOMIC_RELAXED, __HIP_MEMORY_SCOPE_AGENT);
        unsigned prev = __hip_atomic_fetch_add(counter, 1u,
                           __ATOMIC_ACQ_REL, __HIP_MEMORY_SCOPE_AGENT);
        amLast = (prev == (unsigned)(nblocks - 1));
    }
    __syncthreads();

    // ---- last block: deterministic fixed-order final reduce
    if (amLast) {
        double s = 0.0;
        for (int i = tid; i < nblocks; i += TPB)
            s += (double)__hip_atomic_load(&partial[i],
                           __ATOMIC_RELAXED, __HIP_MEMORY_SCOPE_AGENT);
        #pragma unroll
        for (int off = 32; off > 0; off >>= 1)
            s += __shfl_down(s, off, 64);
        __shared__ double dsum[4];
        if (lane == 0) dsum[wid] = s;
        __syncthreads();
        if (tid == 0)
            out[0] = (float)((dsum[0] + dsum[1] + dsum[2] + dsum[3]) * (double)inv_n);
    }
}

extern "C" void kernel_launch(void* const* d_in, const int* in_sizes, int n_in,
                              void* d_out, int out_size, void* d_ws, size_t ws_size,
                              hipStream_t stream) {
    const float* pred = (const float*)d_in[0];
    const float* tgt  = (const float*)d_in[1];
    float* out = (float*)d_out;

    int total_elems = in_sizes[0];          // N * S * S * 30
    int ncells = total_elems / CELLF;       // N * 196
    int N = ncells / (S_DIM * S_DIM);       // 4096

    int nblocks = (ncells + TPB - 1) / TPB; // 3136
    float* partial = (float*)d_ws;          // nblocks * 4 B
    unsigned* counter = (unsigned*)((char*)d_ws + 16384);

    hipMemsetAsync(counter, 0, sizeof(unsigned), stream);
    yolo_loss_kernel<<<nblocks, TPB, 0, stream>>>(
        pred, tgt, partial, counter, out, ncells, nblocks, 1.0f / (float)N);
}

// Round 4
// 82.629 us; speedup vs baseline: 2.3918x; 2.3918x over previous
//
#include <hip/hip_runtime.h>

// YOLO loss: pred/target (N,14,14,30) fp32 -> scalar.
// S=14, B=2, C=20, cell stride = 30 floats = 120 bytes.
//
// R4 = R2 two-kernel structure (plain stores, separate tiny reduce kernel;
// NO cross-block atomics — agent-scope ACQ_REL RMWs caused ~190 MB of L2
// coherence writeback traffic on this 8-XCD chip, R3 post-mortem) +
// R3's two-phase 31 KB LDS staging (one buffer reused pred-then-tgt)
// for ~4 blocks/CU instead of R2's 2.

#define S_DIM 14
#define CELLF 30
#define TPB 256
#define CHUNKF (TPB * CELLF)   // 7680 floats per array per block
#define CHUNK4 (CHUNKF / 4)    // 1920 float4 per array per block

constexpr float LAMBDA_COORD = 5.0f;
constexpr float LAMBDA_NOOBJ = 0.5f;
constexpr float EPSF = 1e-7f;

__device__ __forceinline__ float iou_xywh(float cx1, float cy1, float w1, float h1,
                                          float cx2, float cy2, float w2, float h2) {
    float ix1 = fmaxf(cx1 - 0.5f * w1, cx2 - 0.5f * w2);
    float iy1 = fmaxf(cy1 - 0.5f * h1, cy2 - 0.5f * h2);
    float ix2 = fminf(cx1 + 0.5f * w1, cx2 + 0.5f * w2);
    float iy2 = fminf(cy1 + 0.5f * h1, cy2 + 0.5f * h2);
    float inter = fmaxf(ix2 - ix1, 0.0f) * fmaxf(iy2 - iy1, 0.0f);
    float uni = w1 * h1 + w2 * h2 - inter + EPSF;
    return inter / uni;
}

// Stage one array's block-chunk (CHUNK4 float4) into lds, then read this
// thread's cell into dst[30].
__device__ __forceinline__ void stage_and_gather(
        const float4* __restrict__ src4, size_t base4,
        float* lds, int tid, float dst[CELLF]) {
    float4 st[8];
    #pragma unroll
    for (int k = 0; k < 8; ++k) {
        int i = tid + k * TPB;
        if (i < CHUNK4) st[k] = src4[base4 + i];   // coalesced 1KB/wave-instr
    }
    #pragma unroll
    for (int k = 0; k < 8; ++k) {
        int i = tid + k * TPB;
        if (i < CHUNK4) reinterpret_cast<float4*>(lds)[i] = st[k];
    }
    __syncthreads();
    #pragma unroll
    for (int k = 0; k < CELLF; ++k) dst[k] = lds[tid * CELLF + k];  // stride-30: 4-way, ok
    __syncthreads();
}

__global__ __launch_bounds__(TPB) void yolo_loss_kernel(
        const float* __restrict__ pred,
        const float* __restrict__ tgt,
        float* __restrict__ partial,
        int ncells) {
    __shared__ float lds[CHUNKF];   // 30720 B -> ~4 blocks/CU

    const int tid = threadIdx.x;
    const size_t base4 = (size_t)blockIdx.x * CHUNK4;

    float p[CELLF], t[CELLF];
    stage_and_gather(reinterpret_cast<const float4*>(pred), base4, lds, tid, p);
    stage_and_gather(reinterpret_cast<const float4*>(tgt),  base4, lds, tid, t);

    // grid is exact (ncells = 3136*256); no tail handling needed
    // layout per cell: [0..4]=box0 cx,cy,w,h,conf  [5..9]=box1  [10..29]=classes
    float iou00 = iou_xywh(p[0], p[1], p[2], p[3], t[0], t[1], t[2], t[3]);
    float iou10 = iou_xywh(p[5], p[6], p[7], p[8], t[0], t[1], t[2], t[3]);
    float iou11 = iou_xywh(p[5], p[6], p[7], p[8], t[5], t[6], t[7], t[8]);

    bool obj = t[4] > 0.0f;          // tgt conf of box0 (== obj mask)
    bool best1 = iou10 > iou00;      // argmax first-max tie-break

    float d0 = p[4] - t[4];  float c0 = d0 * d0;
    float d1 = p[9] - t[9];  float c1 = d1 * d1;
    float conf_best  = best1 ? c1 : c0;
    float conf_other = best1 ? c0 : c1;

    float iou_pair_best = best1 ? iou11 : iou00;
    float coord = 1.0f - sqrtf(fmaxf(iou_pair_best, EPSF));  // ALPHA=0.5

    float cls = 0.0f;
    #pragma unroll
    for (int k = 0; k < 20; ++k) {
        float d = p[10 + k] - t[10 + k];
        cls = fmaf(d, d, cls);
    }

    float loss_obj   = obj ? conf_best : 0.0f;
    float loss_noobj = obj ? conf_other : (c0 + c1);
    float loss_coord = obj ? coord : 0.0f;
    float loss_cls   = obj ? cls : 0.0f;

    float loss = LAMBDA_COORD * loss_coord + loss_obj
               + LAMBDA_NOOBJ * loss_noobj + loss_cls;

    // ---- block reduce (wave shuffle + LDS)
    #pragma unroll
    for (int off = 32; off > 0; off >>= 1)
        loss += __shfl_down(loss, off, 64);

    __shared__ float wsum[4];
    int lane = tid & 63;
    int wid  = tid >> 6;
    if (lane == 0) wsum[wid] = loss;
    __syncthreads();
    if (tid == 0)
        partial[blockIdx.x] = wsum[0] + wsum[1] + wsum[2] + wsum[3];
}

__global__ __launch_bounds__(256) void yolo_reduce_kernel(
        const float* __restrict__ partial, int n,
        float* __restrict__ out, float inv_n) {
    double s = 0.0;
    for (int i = threadIdx.x; i < n; i += 256)
        s += (double)partial[i];
    #pragma unroll
    for (int off = 32; off > 0; off >>= 1)
        s += __shfl_down(s, off, 64);
    __shared__ double wsum[4];
    int lane = threadIdx.x & 63;
    int wid  = threadIdx.x >> 6;
    if (lane == 0) wsum[wid] = s;
    __syncthreads();
    if (threadIdx.x == 0) {
        double tot = wsum[0] + wsum[1] + wsum[2] + wsum[3];
        out[0] = (float)(tot * (double)inv_n);
    }
}

extern "C" void kernel_launch(void* const* d_in, const int* in_sizes, int n_in,
                              void* d_out, int out_size, void* d_ws, size_t ws_size,
                              hipStream_t stream) {
    const float* pred = (const float*)d_in[0];
    const float* tgt  = (const float*)d_in[1];
    float* out = (float*)d_out;

    int total_elems = in_sizes[0];          // N * S * S * 30
    int ncells = total_elems / CELLF;       // N * 196
    int N = ncells / (S_DIM * S_DIM);       // 4096

    int nblocks = (ncells + TPB - 1) / TPB; // 3136 (exact: 802816 = 3136*256)
    float* partial = (float*)d_ws;          // nblocks * 4 B

    yolo_loss_kernel<<<nblocks, TPB, 0, stream>>>(pred, tgt, partial, ncells);
    yolo_reduce_kernel<<<1, 256, 0, stream>>>(partial, nblocks, out, 1.0f / (float)N);
}

// Round 5
// 37.929 us; speedup vs baseline: 5.2105x; 2.1785x over previous
//
#include <hip/hip_runtime.h>

// YOLO loss: pred/target (N,14,14,30) fp32 -> scalar.
// S=14, B=2, C=20, cell stride = 30 floats = 120 bytes.
//
// R5: two-phase 31 KB LDS staging (pred -> regs, reuse buffer for tgt),
// fully INLINED with unconditional statically-indexed arrays.
// R3/R4 post-mortem: passing the staging/dest arrays through a helper
// function (pointer param) sent them to scratch -> 188 MB of HBM write
// traffic (VGPR count fell 88->44). Keep everything in the kernel body.
// Two-kernel reduce (no cross-block atomics).

#define S_DIM 14
#define CELLF 30
#define TPB 256
#define CHUNKF (TPB * CELLF)   // 7680 floats per array per block
#define CHUNK2 (CHUNKF / 2)    // 3840 float2 per array per block

constexpr float LAMBDA_COORD = 5.0f;
constexpr float LAMBDA_NOOBJ = 0.5f;
constexpr float EPSF = 1e-7f;

__device__ __forceinline__ float iou_xywh(float cx1, float cy1, float w1, float h1,
                                          float cx2, float cy2, float w2, float h2) {
    float ix1 = fmaxf(cx1 - 0.5f * w1, cx2 - 0.5f * w2);
    float iy1 = fmaxf(cy1 - 0.5f * h1, cy2 - 0.5f * h2);
    float ix2 = fminf(cx1 + 0.5f * w1, cx2 + 0.5f * w2);
    float iy2 = fminf(cy1 + 0.5f * h1, cy2 + 0.5f * h2);
    float inter = fmaxf(ix2 - ix1, 0.0f) * fmaxf(iy2 - iy1, 0.0f);
    float uni = w1 * h1 + w2 * h2 - inter + EPSF;
    return inter / uni;
}

__global__ __launch_bounds__(TPB, 4) void yolo_loss_kernel(
        const float* __restrict__ pred,
        const float* __restrict__ tgt,
        float* __restrict__ partial) {
    __shared__ float lds[CHUNKF];   // 30720 B

    const int tid = threadIdx.x;
    const size_t base2 = (size_t)blockIdx.x * CHUNK2;   // float2 index into each array
    const float2* pred2 = reinterpret_cast<const float2*>(pred);
    const float2* tgt2  = reinterpret_cast<const float2*>(tgt);
    float2* lds2 = reinterpret_cast<float2*>(lds);

    // ---------------- phase 1: pred -> LDS -> p[30] ----------------
    float2 s[15];
    #pragma unroll
    for (int k = 0; k < 15; ++k)
        s[k] = pred2[base2 + tid + k * TPB];            // coalesced, exact cover
    #pragma unroll
    for (int k = 0; k < 15; ++k)
        lds2[tid + k * TPB] = s[k];                     // linear, conflict-free
    __syncthreads();

    float p[CELLF];
    #pragma unroll
    for (int k = 0; k < 15; ++k) {
        float2 v = lds2[tid * 15 + k];                  // cell gather, 4-way bank
        p[2 * k] = v.x; p[2 * k + 1] = v.y;
    }
    __syncthreads();

    // ---------------- phase 2: tgt -> LDS -> t[30] ----------------
    #pragma unroll
    for (int k = 0; k < 15; ++k)
        s[k] = tgt2[base2 + tid + k * TPB];
    #pragma unroll
    for (int k = 0; k < 15; ++k)
        lds2[tid + k * TPB] = s[k];
    __syncthreads();

    float t[CELLF];
    #pragma unroll
    for (int k = 0; k < 15; ++k) {
        float2 v = lds2[tid * 15 + k];
        t[2 * k] = v.x; t[2 * k + 1] = v.y;
    }

    // ---------------- per-cell loss ----------------
    // layout per cell: [0..4]=box0 cx,cy,w,h,conf  [5..9]=box1  [10..29]=classes
    float iou00 = iou_xywh(p[0], p[1], p[2], p[3], t[0], t[1], t[2], t[3]);
    float iou10 = iou_xywh(p[5], p[6], p[7], p[8], t[0], t[1], t[2], t[3]);
    float iou11 = iou_xywh(p[5], p[6], p[7], p[8], t[5], t[6], t[7], t[8]);

    bool obj = t[4] > 0.0f;          // tgt conf of box0 (== obj mask)
    bool best1 = iou10 > iou00;      // argmax first-max tie-break

    float d0 = p[4] - t[4];  float c0 = d0 * d0;
    float d1 = p[9] - t[9];  float c1 = d1 * d1;
    float conf_best  = best1 ? c1 : c0;
    float conf_other = best1 ? c0 : c1;

    float iou_pair_best = best1 ? iou11 : iou00;
    float coord = 1.0f - sqrtf(fmaxf(iou_pair_best, EPSF));  // ALPHA=0.5

    float cls = 0.0f;
    #pragma unroll
    for (int k = 0; k < 20; ++k) {
        float d = p[10 + k] - t[10 + k];
        cls = fmaf(d, d, cls);
    }

    float loss_obj   = obj ? conf_best : 0.0f;
    float loss_noobj = obj ? conf_other : (c0 + c1);
    float loss_coord = obj ? coord : 0.0f;
    float loss_cls   = obj ? cls : 0.0f;

    float loss = LAMBDA_COORD * loss_coord + loss_obj
               + LAMBDA_NOOBJ * loss_noobj + loss_cls;

    // ---------------- block reduce ----------------
    #pragma unroll
    for (int off = 32; off > 0; off >>= 1)
        loss += __shfl_down(loss, off, 64);

    __shared__ float wsum[4];
    int lane = tid & 63;
    int wid  = tid >> 6;
    if (lane == 0) wsum[wid] = loss;
    __syncthreads();
    if (tid == 0)
        partial[blockIdx.x] = wsum[0] + wsum[1] + wsum[2] + wsum[3];
}

__global__ __launch_bounds__(256) void yolo_reduce_kernel(
        const float* __restrict__ partial, int n,
        float* __restrict__ out, float inv_n) {
    double s = 0.0;
    for (int i = threadIdx.x; i < n; i += 256)
        s += (double)partial[i];
    #pragma unroll
    for (int off = 32; off > 0; off >>= 1)
        s += __shfl_down(s, off, 64);
    __shared__ double wsum[4];
    int lane = threadIdx.x & 63;
    int wid  = threadIdx.x >> 6;
    if (lane == 0) wsum[wid] = s;
    __syncthreads();
    if (threadIdx.x == 0) {
        double tot = wsum[0] + wsum[1] + wsum[2] + wsum[3];
        out[0] = (float)(tot * (double)inv_n);
    }
}

extern "C" void kernel_launch(void* const* d_in, const int* in_sizes, int n_in,
                              void* d_out, int out_size, void* d_ws, size_t ws_size,
                              hipStream_t stream) {
    const float* pred = (const float*)d_in[0];
    const float* tgt  = (const float*)d_in[1];
    float* out = (float*)d_out;

    int total_elems = in_sizes[0];          // N * S * S * 30
    int ncells = total_elems / CELLF;       // N * 196 = 802816 (exact 3136*256)
    int N = ncells / (S_DIM * S_DIM);       // 4096

    int nblocks = ncells / TPB;             // 3136
    float* partial = (float*)d_ws;          // nblocks * 4 B

    yolo_loss_kernel<<<nblocks, TPB, 0, stream>>>(pred, tgt, partial);
    yolo_reduce_kernel<<<1, 256, 0, stream>>>(partial, nblocks, out, 1.0f / (float)N);
}